// Round 1
// baseline (69.122 us; speedup 1.0000x reference)
//
#include <hip/hip_runtime.h>

#define LSTEPS 64
#define NPAIRA 256
#define NPAIRB 255

__device__ __forceinline__ float2 cmul(float2 a, float2 b) {
  return make_float2(fmaf(a.x, b.x, -(a.y * b.y)), fmaf(a.x, b.y, a.y * b.x));
}
// a*b + c (complex)
__device__ __forceinline__ float2 cfma(float2 a, float2 b, float2 c) {
  return make_float2(fmaf(a.x, b.x, fmaf(-a.y, b.y, c.x)),
                     fmaf(a.x, b.y, fmaf(a.y, b.x, c.y)));
}

// One block per scan step l. Threads 0..255 -> layer-A MZIs, 256..510 -> layer-B MZIs.
// Coefficients per MZI: na = C1*a + C2*b ; nb = C3*a + C4*b
//   C1 = ephi*t, C2 = i*u, C3 = i*ephi*u, C4 = -t
//   with ephi = e^{i ang0}, eth = e^{i ang1}, t = (eth-1)/2, u = (eth+1)/2
__global__ __launch_bounds__(512) void precompute_coeffs(
    const float* __restrict__ a0, const float* __restrict__ a1,
    const float* __restrict__ b0, const float* __restrict__ b1,
    float4* __restrict__ cA, float4* __restrict__ cB)
{
  const int l = blockIdx.x;
  const int tid = threadIdx.x;
  const bool isA = tid < NPAIRA;
  const int j = isA ? tid : tid - NPAIRA;
  if (!isA && j >= NPAIRB) return;
  float ang0, ang1;
  if (isA) { ang0 = a0[l * NPAIRA + j]; ang1 = a1[l * NPAIRA + j]; }
  else     { ang0 = b0[l * NPAIRB + j]; ang1 = b1[l * NPAIRB + j]; }
  float se, ce, st, ct;
  sincosf(ang0, &se, &ce);   // ephi = (ce, se)
  sincosf(ang1, &st, &ct);   // eth  = (ct, st)
  float2 ephi = make_float2(ce, se);
  float2 tt = make_float2(0.5f * (ct - 1.0f), 0.5f * st);
  float2 uu = make_float2(0.5f * (ct + 1.0f), 0.5f * st);
  float2 C1 = cmul(ephi, tt);
  float2 C2 = make_float2(-uu.y, uu.x);
  float2 eu = cmul(ephi, uu);
  float2 C3 = make_float2(-eu.y, eu.x);
  float2 C4 = make_float2(-tt.x, -tt.y);
  float4* dst = isA ? (cA + (size_t)(l * NPAIRA + j) * 2)
                    : (cB + (size_t)(l * NPAIRB + j) * 2);
  dst[0] = make_float4(C1.x, C1.y, C2.x, C2.y);
  dst[1] = make_float4(C3.x, C3.y, C4.x, C4.y);
}

// 256 threads; thread t owns features (2t, 2t+1) in registers for R batch rows.
// Layer B pairs (2t+1, 2t+2): neighbor exchange through LDS (crosses wave boundaries).
template <int R>
__global__ __launch_bounds__(256) void mesh_kernel(
    const float4* __restrict__ xin, const float4* __restrict__ cA,
    const float4* __restrict__ cB, const float* __restrict__ omega,
    float4* __restrict__ out)
{
  const int t = threadIdx.x;
  const int row0 = blockIdx.x * R;
  __shared__ float2 exA[R][NPAIRA];  // layer-A 'na' (even-position) values
  __shared__ float2 exB[R][NPAIRA];  // layer-B 'nb' values heading to thread t+1

  float2 xa[R], xb[R];
#pragma unroll
  for (int r = 0; r < R; ++r) {
    float4 v = xin[(size_t)(row0 + r) * NPAIRA + t];
    xa[r] = make_float2(v.x, v.y);
    xb[r] = make_float2(v.z, v.w);
  }

  for (int l = 0; l < LSTEPS; ++l) {
    // ---- layer A: pair (2t, 2t+1), fully thread-local ----
    float4 ka0 = cA[(size_t)(l * NPAIRA + t) * 2 + 0];
    float4 ka1 = cA[(size_t)(l * NPAIRA + t) * 2 + 1];
    float2 c1 = make_float2(ka0.x, ka0.y), c2 = make_float2(ka0.z, ka0.w);
    float2 c3 = make_float2(ka1.x, ka1.y), c4 = make_float2(ka1.z, ka1.w);
#pragma unroll
    for (int r = 0; r < R; ++r) {
      float2 na = cfma(c2, xb[r], cmul(c1, xa[r]));
      float2 nb = cfma(c4, xb[r], cmul(c3, xa[r]));
      xa[r] = na;
      xb[r] = nb;
      exA[r][t] = na;  // publish even-position value for left neighbor
    }
    __syncthreads();
    // ---- layer B: pair (2t+1, 2t+2) = (my xb, right neighbor's xa) ----
    if (t < NPAIRB) {
      float4 kb0 = cB[(size_t)(l * NPAIRB + t) * 2 + 0];
      float4 kb1 = cB[(size_t)(l * NPAIRB + t) * 2 + 1];
      float2 d1 = make_float2(kb0.x, kb0.y), d2 = make_float2(kb0.z, kb0.w);
      float2 d3 = make_float2(kb1.x, kb1.y), d4 = make_float2(kb1.z, kb1.w);
#pragma unroll
      for (int r = 0; r < R; ++r) {
        float2 bv = exA[r][t + 1];
        float2 na = cfma(d2, bv, cmul(d1, xb[r]));
        float2 nb = cfma(d4, bv, cmul(d3, xb[r]));
        xb[r] = na;        // new x[2t+1]
        exB[r][t] = nb;    // new x[2t+2] -> belongs to thread t+1
      }
    }
    __syncthreads();
    if (t > 0) {
#pragma unroll
      for (int r = 0; r < R; ++r) xa[r] = exB[r][t - 1];
    }
    // (x[0] at thread 0 and x[511] at thread 255 pass through layer B)
  }

  // ---- epilogue: multiply by exp(i*omega) and store ----
  float s0, c0, s1, c1;
  sincosf(omega[2 * t + 0], &s0, &c0);
  sincosf(omega[2 * t + 1], &s1, &c1);
  float2 w0 = make_float2(c0, s0), w1 = make_float2(c1, s1);
#pragma unroll
  for (int r = 0; r < R; ++r) {
    float2 oa = cmul(xa[r], w0);
    float2 ob = cmul(xb[r], w1);
    out[(size_t)(row0 + r) * NPAIRA + t] = make_float4(oa.x, oa.y, ob.x, ob.y);
  }
}

extern "C" void kernel_launch(void* const* d_in, const int* in_sizes, int n_in,
                              void* d_out, int out_size, void* d_ws, size_t ws_size,
                              hipStream_t stream) {
  const float* cmplx = (const float*)d_in[0];   // (2048, 512, 2) f32
  const float* a0    = (const float*)d_in[1];   // (64, 256)
  const float* a1    = (const float*)d_in[2];   // (64, 256)
  const float* b0    = (const float*)d_in[3];   // (64, 255)
  const float* b1    = (const float*)d_in[4];   // (64, 255)
  const float* omega = (const float*)d_in[5];   // (512,)

  float4* cA = (float4*)d_ws;                                   // 64*256*2 float4 = 512 KiB
  float4* cB = (float4*)((char*)d_ws + (size_t)LSTEPS * NPAIRA * 2 * sizeof(float4));

  precompute_coeffs<<<LSTEPS, 512, 0, stream>>>(a0, a1, b0, b1, cA, cB);

  constexpr int R = 4;
  const int BATCH = 2048;
  mesh_kernel<R><<<BATCH / R, 256, 0, stream>>>(
      (const float4*)cmplx, cA, cB, omega, (float4*)d_out);
}

// Round 2
// 64.914 us; speedup vs baseline: 1.0648x; 1.0648x over previous
//
#include <hip/hip_runtime.h>

#define LSTEPS 64
#define NPAIRA 256
#define NPAIRB 255

__device__ __forceinline__ float2 cmul(float2 a, float2 b) {
  return make_float2(fmaf(a.x, b.x, -(a.y * b.y)), fmaf(a.x, b.y, a.y * b.x));
}
// a*b + c (complex)
__device__ __forceinline__ float2 cfma(float2 a, float2 b, float2 c) {
  return make_float2(fmaf(a.x, b.x, fmaf(-a.y, b.y, c.x)),
                     fmaf(a.x, b.y, fmaf(a.y, b.x, c.y)));
}

// LDS-ordering-only barrier: drain DS ops, but let global (vmcnt) prefetch
// loads stay in flight across the barrier (unlike __syncthreads, which the
// compiler lowers with a full vmcnt(0) lgkmcnt(0) drain).
__device__ __forceinline__ void lds_barrier() {
  asm volatile("s_waitcnt lgkmcnt(0)" ::: "memory");
  __builtin_amdgcn_s_barrier();
}

__global__ __launch_bounds__(512) void precompute_coeffs(
    const float* __restrict__ a0, const float* __restrict__ a1,
    const float* __restrict__ b0, const float* __restrict__ b1,
    float4* __restrict__ cA, float4* __restrict__ cB)
{
  const int l = blockIdx.x;
  const int tid = threadIdx.x;
  const bool isA = tid < NPAIRA;
  const int j = isA ? tid : tid - NPAIRA;
  if (!isA && j >= NPAIRB) return;
  float ang0, ang1;
  if (isA) { ang0 = a0[l * NPAIRA + j]; ang1 = a1[l * NPAIRA + j]; }
  else     { ang0 = b0[l * NPAIRB + j]; ang1 = b1[l * NPAIRB + j]; }
  float se, ce, st, ct;
  sincosf(ang0, &se, &ce);   // ephi = (ce, se)
  sincosf(ang1, &st, &ct);   // eth  = (ct, st)
  float2 ephi = make_float2(ce, se);
  float2 tt = make_float2(0.5f * (ct - 1.0f), 0.5f * st);
  float2 uu = make_float2(0.5f * (ct + 1.0f), 0.5f * st);
  float2 C1 = cmul(ephi, tt);
  float2 C2 = make_float2(-uu.y, uu.x);
  float2 eu = cmul(ephi, uu);
  float2 C3 = make_float2(-eu.y, eu.x);
  float2 C4 = make_float2(-tt.x, -tt.y);
  float4* dst = isA ? (cA + (size_t)(l * NPAIRA + j) * 2)
                    : (cB + (size_t)(l * NPAIRB + j) * 2);
  dst[0] = make_float4(C1.x, C1.y, C2.x, C2.y);
  dst[1] = make_float4(C3.x, C3.y, C4.x, C4.y);
}

// 256 threads; thread t owns features (2t, 2t+1) in registers for R batch rows.
// Layer B pairs (2t+1, 2t+2): neighbor exchange through LDS.
// Coefficients for step l+1 are prefetched into registers at the top of step l
// and survive the (lgkm-only) barriers.
template <int R>
__global__ __launch_bounds__(256) void mesh_kernel(
    const float4* __restrict__ xin, const float4* __restrict__ cA,
    const float4* __restrict__ cB, const float* __restrict__ omega,
    float4* __restrict__ out)
{
  const int t = threadIdx.x;
  const int row0 = blockIdx.x * R;
  __shared__ float2 exA[R][NPAIRA];  // layer-A 'na' (even-position) values
  __shared__ float2 exB[R][NPAIRA];  // layer-B 'nb' values heading to thread t+1

  float2 xa[R], xb[R];
#pragma unroll
  for (int r = 0; r < R; ++r) {
    float4 v = xin[(size_t)(row0 + r) * NPAIRA + t];
    xa[r] = make_float2(v.x, v.y);
    xb[r] = make_float2(v.z, v.w);
  }

  const bool hasB = (t < NPAIRB);

  // step-0 coefficients
  float4 ka0 = cA[(size_t)(0 * NPAIRA + t) * 2 + 0];
  float4 ka1 = cA[(size_t)(0 * NPAIRA + t) * 2 + 1];
  float4 kb0 = make_float4(0, 0, 0, 0), kb1 = make_float4(0, 0, 0, 0);
  if (hasB) {
    kb0 = cB[(size_t)(0 * NPAIRB + t) * 2 + 0];
    kb1 = cB[(size_t)(0 * NPAIRB + t) * 2 + 1];
  }

  for (int l = 0; l < LSTEPS; ++l) {
    // ---- prefetch step l+1 coefficients (stay in flight across barriers) ----
    const int lp = (l + 1 < LSTEPS) ? l + 1 : l;
    float4 nka0 = cA[(size_t)(lp * NPAIRA + t) * 2 + 0];
    float4 nka1 = cA[(size_t)(lp * NPAIRA + t) * 2 + 1];
    float4 nkb0 = kb0, nkb1 = kb1;
    if (hasB) {
      nkb0 = cB[(size_t)(lp * NPAIRB + t) * 2 + 0];
      nkb1 = cB[(size_t)(lp * NPAIRB + t) * 2 + 1];
    }

    // ---- layer A: pair (2t, 2t+1), thread-local ----
    float2 c1 = make_float2(ka0.x, ka0.y), c2 = make_float2(ka0.z, ka0.w);
    float2 c3 = make_float2(ka1.x, ka1.y), c4 = make_float2(ka1.z, ka1.w);
#pragma unroll
    for (int r = 0; r < R; ++r) {
      float2 na = cfma(c2, xb[r], cmul(c1, xa[r]));
      float2 nb = cfma(c4, xb[r], cmul(c3, xa[r]));
      xa[r] = na;
      xb[r] = nb;
      exA[r][t] = na;  // publish even-position value for left neighbor
    }
    lds_barrier();

    // ---- layer B: pair (2t+1, 2t+2) = (my xb, right neighbor's post-A xa) ----
    if (hasB) {
      float2 d1 = make_float2(kb0.x, kb0.y), d2 = make_float2(kb0.z, kb0.w);
      float2 d3 = make_float2(kb1.x, kb1.y), d4 = make_float2(kb1.z, kb1.w);
#pragma unroll
      for (int r = 0; r < R; ++r) {
        float2 bv = exA[r][t + 1];
        float2 na = cfma(d2, bv, cmul(d1, xb[r]));
        float2 nb = cfma(d4, bv, cmul(d3, xb[r]));
        xb[r] = na;        // new x[2t+1]
        exB[r][t] = nb;    // new x[2t+2] -> belongs to thread t+1
      }
    }
    lds_barrier();
    if (t > 0) {
#pragma unroll
      for (int r = 0; r < R; ++r) xa[r] = exB[r][t - 1];
    }
    // (x[0] at thread 0 and x[511] at thread 255 pass through layer B)

    ka0 = nka0; ka1 = nka1; kb0 = nkb0; kb1 = nkb1;
  }

  // ---- epilogue: multiply by exp(i*omega) and store ----
  float s0, c0, s1, c1;
  sincosf(omega[2 * t + 0], &s0, &c0);
  sincosf(omega[2 * t + 1], &s1, &c1);
  float2 w0 = make_float2(c0, s0), w1 = make_float2(c1, s1);
#pragma unroll
  for (int r = 0; r < R; ++r) {
    float2 oa = cmul(xa[r], w0);
    float2 ob = cmul(xb[r], w1);
    out[(size_t)(row0 + r) * NPAIRA + t] = make_float4(oa.x, oa.y, ob.x, ob.y);
  }
}

extern "C" void kernel_launch(void* const* d_in, const int* in_sizes, int n_in,
                              void* d_out, int out_size, void* d_ws, size_t ws_size,
                              hipStream_t stream) {
  const float* cmplx = (const float*)d_in[0];   // (2048, 512, 2) f32
  const float* a0    = (const float*)d_in[1];   // (64, 256)
  const float* a1    = (const float*)d_in[2];   // (64, 256)
  const float* b0    = (const float*)d_in[3];   // (64, 255)
  const float* b1    = (const float*)d_in[4];   // (64, 255)
  const float* omega = (const float*)d_in[5];   // (512,)

  float4* cA = (float4*)d_ws;                                   // 64*256*2 float4 = 512 KiB
  float4* cB = (float4*)((char*)d_ws + (size_t)LSTEPS * NPAIRA * 2 * sizeof(float4));

  precompute_coeffs<<<LSTEPS, 512, 0, stream>>>(a0, a1, b0, b1, cA, cB);

  constexpr int R = 2;                 // 1024 blocks -> 4 blocks/CU, 16 waves/CU
  const int BATCH = 2048;
  mesh_kernel<R><<<BATCH / R, 256, 0, stream>>>(
      (const float4*)cmplx, cA, cB, omega, (float4*)d_out);
}

// Round 3
// 56.899 us; speedup vs baseline: 1.2148x; 1.1409x over previous
//
#include <hip/hip_runtime.h>

#define LSTEPS 64
#define NPAIRA 256
#define NPAIRB 255
#define NF 512
#define MBATCH 2048

typedef __attribute__((ext_vector_type(8))) short bf16x8;
typedef __attribute__((ext_vector_type(4))) float f32x4;
typedef __attribute__((ext_vector_type(4))) int i32x4;
typedef __attribute__((ext_vector_type(8))) unsigned short u16x8;

__device__ __forceinline__ float2 cmul(float2 a, float2 b) {
  return make_float2(fmaf(a.x, b.x, -(a.y * b.y)), fmaf(a.x, b.y, a.y * b.x));
}
__device__ __forceinline__ float2 cfma(float2 a, float2 b, float2 c) {
  return make_float2(fmaf(a.x, b.x, fmaf(-a.y, b.y, c.x)),
                     fmaf(a.x, b.y, fmaf(a.y, b.x, c.y)));
}
__device__ __forceinline__ unsigned short f2bf(float f) {
  union { float f; unsigned u; } v; v.f = f;
  unsigned r = v.u + 0x7FFF + ((v.u >> 16) & 1);
  return (unsigned short)(r >> 16);
}
__device__ __forceinline__ void lds_barrier() {
  asm volatile("s_waitcnt lgkmcnt(0)" ::: "memory");
  __builtin_amdgcn_s_barrier();
}

// ---------------- coefficient precompute (unchanged) ----------------
__global__ __launch_bounds__(512) void precompute_coeffs(
    const float* __restrict__ a0, const float* __restrict__ a1,
    const float* __restrict__ b0, const float* __restrict__ b1,
    float4* __restrict__ cA, float4* __restrict__ cB)
{
  const int l = blockIdx.x;
  const int tid = threadIdx.x;
  const bool isA = tid < NPAIRA;
  const int j = isA ? tid : tid - NPAIRA;
  if (!isA && j >= NPAIRB) return;
  float ang0, ang1;
  if (isA) { ang0 = a0[l * NPAIRA + j]; ang1 = a1[l * NPAIRA + j]; }
  else     { ang0 = b0[l * NPAIRB + j]; ang1 = b1[l * NPAIRB + j]; }
  float se, ce, st, ct;
  sincosf(ang0, &se, &ce);
  sincosf(ang1, &st, &ct);
  float2 ephi = make_float2(ce, se);
  float2 tt = make_float2(0.5f * (ct - 1.0f), 0.5f * st);
  float2 uu = make_float2(0.5f * (ct + 1.0f), 0.5f * st);
  float2 C1 = cmul(ephi, tt);
  float2 C2 = make_float2(-uu.y, uu.x);
  float2 eu = cmul(ephi, uu);
  float2 C3 = make_float2(-eu.y, eu.x);
  float2 C4 = make_float2(-tt.x, -tt.y);
  float4* dst = isA ? (cA + (size_t)(l * NPAIRA + j) * 2)
                    : (cB + (size_t)(l * NPAIRB + j) * 2);
  dst[0] = make_float4(C1.x, C1.y, C2.x, C2.y);
  dst[1] = make_float4(C3.x, C3.y, C4.x, C4.y);
}

// ---------------- mesh applied to identity: builds Bt[i][j] = e^{i w_i} U[i][j] (bf16 planes) ----------------
__global__ __launch_bounds__(256) void mesh_identity(
    const float4* __restrict__ cA, const float4* __restrict__ cB,
    const float* __restrict__ omega,
    unsigned short* __restrict__ Btr, unsigned short* __restrict__ Bti)
{
  const int t = threadIdx.x;
  const int j = blockIdx.x;           // basis index (column of U)
  __shared__ float2 exA[NPAIRA];
  __shared__ float2 exB[NPAIRA];

  float2 xa = make_float2((2 * t == j) ? 1.0f : 0.0f, 0.0f);
  float2 xb = make_float2((2 * t + 1 == j) ? 1.0f : 0.0f, 0.0f);

  const bool hasB = (t < NPAIRB);
  float4 ka0 = cA[(size_t)t * 2 + 0];
  float4 ka1 = cA[(size_t)t * 2 + 1];
  float4 kb0 = make_float4(0, 0, 0, 0), kb1 = make_float4(0, 0, 0, 0);
  if (hasB) {
    kb0 = cB[(size_t)t * 2 + 0];
    kb1 = cB[(size_t)t * 2 + 1];
  }

  for (int l = 0; l < LSTEPS; ++l) {
    const int lp = (l + 1 < LSTEPS) ? l + 1 : l;
    float4 nka0 = cA[(size_t)(lp * NPAIRA + t) * 2 + 0];
    float4 nka1 = cA[(size_t)(lp * NPAIRA + t) * 2 + 1];
    float4 nkb0 = kb0, nkb1 = kb1;
    if (hasB) {
      nkb0 = cB[(size_t)(lp * NPAIRB + t) * 2 + 0];
      nkb1 = cB[(size_t)(lp * NPAIRB + t) * 2 + 1];
    }

    float2 c1 = make_float2(ka0.x, ka0.y), c2 = make_float2(ka0.z, ka0.w);
    float2 c3 = make_float2(ka1.x, ka1.y), c4 = make_float2(ka1.z, ka1.w);
    {
      float2 na = cfma(c2, xb, cmul(c1, xa));
      float2 nb = cfma(c4, xb, cmul(c3, xa));
      xa = na; xb = nb;
      exA[t] = na;
    }
    lds_barrier();

    if (hasB) {
      float2 d1 = make_float2(kb0.x, kb0.y), d2 = make_float2(kb0.z, kb0.w);
      float2 d3 = make_float2(kb1.x, kb1.y), d4 = make_float2(kb1.z, kb1.w);
      float2 bv = exA[t + 1];
      float2 na = cfma(d2, bv, cmul(d1, xb));
      float2 nb = cfma(d4, bv, cmul(d3, xb));
      xb = na;
      exB[t] = nb;
    }
    lds_barrier();
    if (t > 0) xa = exB[t - 1];

    ka0 = nka0; ka1 = nka1; kb0 = nkb0; kb1 = nkb1;
  }

  // epilogue: apply exp(i*omega) (folds the final phase into U'), store transposed bf16
  float s0, c0v, s1, c1v;
  sincosf(omega[2 * t + 0], &s0, &c0v);
  sincosf(omega[2 * t + 1], &s1, &c1v);
  float2 oa = cmul(xa, make_float2(c0v, s0));
  float2 ob = cmul(xb, make_float2(c1v, s1));
  Btr[(size_t)(2 * t + 0) * NF + j] = f2bf(oa.x);
  Bti[(size_t)(2 * t + 0) * NF + j] = f2bf(oa.y);
  Btr[(size_t)(2 * t + 1) * NF + j] = f2bf(ob.x);
  Bti[(size_t)(2 * t + 1) * NF + j] = f2bf(ob.y);
}

// ---------------- complex GEMM: Y[r][i] = sum_j X[r][j] * Bt[i][j] ----------------
#define BM 64
#define BN 64
#define KB 64
#define LDT 72   // LDS leading dim in bf16 elems (pad 64->72: 2-way bank aliasing only)

__global__ __launch_bounds__(256) void cgemm_kernel(
    const float2* __restrict__ X,                 // (2048, 512) complex
    const unsigned short* __restrict__ Btr,       // (512 n, 512 k) bf16 row-major
    const unsigned short* __restrict__ Bti,
    float2* __restrict__ Y)                       // (2048, 512) complex
{
  __shared__ __align__(16) unsigned short Ar[BM][LDT];
  __shared__ __align__(16) unsigned short Ai[BM][LDT];
  __shared__ __align__(16) unsigned short Br[BN][LDT];
  __shared__ __align__(16) unsigned short Bi[BN][LDT];

  const int tid = threadIdx.x;
  const int w = tid >> 6;         // wave 0..3 (M-split)
  const int l = tid & 63;
  const int bm = (blockIdx.x & 31) * BM;     // 32 m-tiles
  const int bn = (blockIdx.x >> 5) * BN;     // 8 n-tiles

  f32x4 acc_r[4], acc_i[4];
#pragma unroll
  for (int nf = 0; nf < 4; ++nf) {
    acc_r[nf] = (f32x4){0.f, 0.f, 0.f, 0.f};
    acc_i[nf] = (f32x4){0.f, 0.f, 0.f, 0.f};
  }

  // staging mapping: 256 threads cover 64 rows x 64 k (16 elems each)
  const int sr = tid >> 2;            // row 0..63 within tile
  const int sk = (tid & 3) * 16;      // k offset {0,16,32,48}

  for (int k0 = 0; k0 < NF; k0 += KB) {
    // ---- issue global loads + convert BEFORE the barrier (overlaps prev compute) ----
    const float4* srcA = (const float4*)(X + (size_t)(bm + sr) * NF + k0 + sk);
    u16x8 vr0, vr1, vi0, vi1;
#pragma unroll
    for (int q = 0; q < 4; ++q) {
      float4 v = srcA[q];
      vr0[2 * q] = f2bf(v.x); vi0[2 * q] = f2bf(v.y);
      vr0[2 * q + 1] = f2bf(v.z); vi0[2 * q + 1] = f2bf(v.w);
    }
#pragma unroll
    for (int q = 0; q < 4; ++q) {
      float4 v = srcA[4 + q];
      vr1[2 * q] = f2bf(v.x); vi1[2 * q] = f2bf(v.y);
      vr1[2 * q + 1] = f2bf(v.z); vi1[2 * q + 1] = f2bf(v.w);
    }
    const uint4* gbr = (const uint4*)(Btr + (size_t)(bn + sr) * NF + k0 + sk);
    const uint4* gbi = (const uint4*)(Bti + (size_t)(bn + sr) * NF + k0 + sk);
    uint4 br0 = gbr[0], br1 = gbr[1];
    uint4 bi0 = gbi[0], bi1 = gbi[1];

    if (k0 > 0) __syncthreads();   // previous compute finished reading LDS

    *(u16x8*)&Ar[sr][sk]     = vr0;
    *(u16x8*)&Ar[sr][sk + 8] = vr1;
    *(u16x8*)&Ai[sr][sk]     = vi0;
    *(u16x8*)&Ai[sr][sk + 8] = vi1;
    *(uint4*)&Br[sr][sk]     = br0;
    *(uint4*)&Br[sr][sk + 8] = br1;
    *(uint4*)&Bi[sr][sk]     = bi0;
    *(uint4*)&Bi[sr][sk + 8] = bi1;

    __syncthreads();

    // ---- compute: 2 k-slices of 32 ----
#pragma unroll
    for (int kk = 0; kk < 2; ++kk) {
      const int ko = kk * 32 + (l >> 4) * 8;
      bf16x8 afr = *(const bf16x8*)&Ar[w * 16 + (l & 15)][ko];
      bf16x8 afi = *(const bf16x8*)&Ai[w * 16 + (l & 15)][ko];
      i32x4 neg = (i32x4)afi ^ (int)0x80008000;
      bf16x8 afin = (bf16x8)neg;     // -Ai
#pragma unroll
      for (int nf = 0; nf < 4; ++nf) {
        bf16x8 bfr = *(const bf16x8*)&Br[nf * 16 + (l & 15)][ko];
        bf16x8 bfi = *(const bf16x8*)&Bi[nf * 16 + (l & 15)][ko];
        acc_r[nf] = __builtin_amdgcn_mfma_f32_16x16x32_bf16(afr,  bfr, acc_r[nf], 0, 0, 0);
        acc_r[nf] = __builtin_amdgcn_mfma_f32_16x16x32_bf16(afin, bfi, acc_r[nf], 0, 0, 0);
        acc_i[nf] = __builtin_amdgcn_mfma_f32_16x16x32_bf16(afr,  bfi, acc_i[nf], 0, 0, 0);
        acc_i[nf] = __builtin_amdgcn_mfma_f32_16x16x32_bf16(afi,  bfr, acc_i[nf], 0, 0, 0);
      }
    }
  }

  // ---- epilogue: D[row=(l>>4)*4+reg][col=l&15] per 16x16 fragment ----
  const int dn0 = bn + (l & 15);
  const int dm0 = bm + w * 16 + (l >> 4) * 4;
#pragma unroll
  for (int nf = 0; nf < 4; ++nf) {
#pragma unroll
    for (int r = 0; r < 4; ++r) {
      Y[(size_t)(dm0 + r) * NF + dn0 + nf * 16] =
          make_float2(acc_r[nf][r], acc_i[nf][r]);
    }
  }
}

extern "C" void kernel_launch(void* const* d_in, const int* in_sizes, int n_in,
                              void* d_out, int out_size, void* d_ws, size_t ws_size,
                              hipStream_t stream) {
  const float* cmplx = (const float*)d_in[0];   // (2048, 512, 2) f32
  const float* a0    = (const float*)d_in[1];
  const float* a1    = (const float*)d_in[2];
  const float* b0    = (const float*)d_in[3];
  const float* b1    = (const float*)d_in[4];
  const float* omega = (const float*)d_in[5];

  size_t off = 0;
  float4* cA = (float4*)((char*)d_ws + off); off += (size_t)LSTEPS * NPAIRA * 2 * sizeof(float4); // 512KB
  float4* cB = (float4*)((char*)d_ws + off); off += (size_t)LSTEPS * NPAIRB * 2 * sizeof(float4); // 510KB
  unsigned short* Btr = (unsigned short*)((char*)d_ws + off); off += (size_t)NF * NF * 2;         // 512KB
  unsigned short* Bti = (unsigned short*)((char*)d_ws + off); off += (size_t)NF * NF * 2;         // 512KB

  precompute_coeffs<<<LSTEPS, 512, 0, stream>>>(a0, a1, b0, b1, cA, cB);
  mesh_identity<<<NF, 256, 0, stream>>>(cA, cB, omega, Btr, Bti);
  cgemm_kernel<<<(MBATCH / BM) * (NF / BN), 256, 0, stream>>>(
      (const float2*)cmplx, Btr, Bti, (float2*)d_out);
}

// Round 4
// 54.288 us; speedup vs baseline: 1.2732x; 1.0481x over previous
//
#include <hip/hip_runtime.h>

#define LSTEPS 64
#define NF 512
#define MB 2048
#define CSTRIDE 256   // padded per-step pair stride for both cA and cB (float4-pairs)

typedef __attribute__((ext_vector_type(8))) short bf16x8;
typedef __attribute__((ext_vector_type(4))) float f32x4;
typedef __attribute__((ext_vector_type(4))) int i32x4;

__device__ __forceinline__ float2 cmul(float2 a, float2 b) {
  return make_float2(fmaf(a.x, b.x, -(a.y * b.y)), fmaf(a.x, b.y, a.y * b.x));
}
__device__ __forceinline__ float2 cfma(float2 a, float2 b, float2 c) {
  return make_float2(fmaf(a.x, b.x, fmaf(-a.y, b.y, c.x)),
                     fmaf(a.x, b.y, fmaf(a.y, b.x, c.y)));
}
__device__ __forceinline__ unsigned short f2bf(float f) {
  union { float f; unsigned u; } v; v.f = f;
  unsigned r = v.u + 0x7FFF + ((v.u >> 16) & 1);
  return (unsigned short)(r >> 16);
}

// ---------------- K1: coeff precompute + U-plane zero + X->bf16 planes ----------------
__global__ __launch_bounds__(256) void prep_kernel(
    const float* __restrict__ a0, const float* __restrict__ a1,
    const float* __restrict__ b0, const float* __restrict__ b1,
    const float4* __restrict__ Xf,     // (2048*512/2) float4 = 2 complex each
    float4* __restrict__ cA, float4* __restrict__ cB,
    unsigned short* __restrict__ Ur, unsigned short* __restrict__ Ui,
    unsigned short* __restrict__ Xr, unsigned short* __restrict__ Xi)
{
  const int bid = blockIdx.x, tid = threadIdx.x;
  if (bid < 64) {
    const int l = bid;
    // A-MZI tid (256 of them)
    {
      float ang0 = a0[l * 256 + tid], ang1 = a1[l * 256 + tid];
      float se, ce, st, ct;
      sincosf(ang0, &se, &ce);
      sincosf(ang1, &st, &ct);
      float2 ephi = make_float2(ce, se);
      float2 tt = make_float2(0.5f * (ct - 1.0f), 0.5f * st);
      float2 uu = make_float2(0.5f * (ct + 1.0f), 0.5f * st);
      float2 C1 = cmul(ephi, tt);
      float2 C2 = make_float2(-uu.y, uu.x);
      float2 eu = cmul(ephi, uu);
      float2 C3 = make_float2(-eu.y, eu.x);
      float2 C4 = make_float2(-tt.x, -tt.y);
      float4* dst = cA + (size_t)(l * CSTRIDE + tid) * 2;
      dst[0] = make_float4(C1.x, C1.y, C2.x, C2.y);
      dst[1] = make_float4(C3.x, C3.y, C4.x, C4.y);
    }
    // B-MZI tid (255 of them), padded stride 256
    if (tid < 255) {
      float ang0 = b0[l * 255 + tid], ang1 = b1[l * 255 + tid];
      float se, ce, st, ct;
      sincosf(ang0, &se, &ce);
      sincosf(ang1, &st, &ct);
      float2 ephi = make_float2(ce, se);
      float2 tt = make_float2(0.5f * (ct - 1.0f), 0.5f * st);
      float2 uu = make_float2(0.5f * (ct + 1.0f), 0.5f * st);
      float2 C1 = cmul(ephi, tt);
      float2 C2 = make_float2(-uu.y, uu.x);
      float2 eu = cmul(ephi, uu);
      float2 C3 = make_float2(-eu.y, eu.x);
      float2 C4 = make_float2(-tt.x, -tt.y);
      float4* dst = cB + (size_t)(l * CSTRIDE + tid) * 2;
      dst[0] = make_float4(C1.x, C1.y, C2.x, C2.y);
      dst[1] = make_float4(C3.x, C3.y, C4.x, C4.y);
    }
  } else if (bid < 96) {
    // zero the 2x512KB U planes (out-of-band entries must be 0 every launch)
    uint4 z = make_uint4(0, 0, 0, 0);
    uint4* pr = (uint4*)Ur;
    uint4* pi = (uint4*)Ui;
    const int idx = (bid - 64) * 256 + tid;    // 8192 threads, plane = 32768 uint4
#pragma unroll
    for (int s = 0; s < 4; ++s) {
      pr[idx + s * 8192] = z;
      pi[idx + s * 8192] = z;
    }
  } else {
    // X (float2) -> Xr/Xi bf16 planes; 4 complex per iter
    const int nthr = 128 * 256;
    const int t0 = (bid - 96) * 256 + tid;
#pragma unroll
    for (int s = 0; s < 8; ++s) {
      const int qi = t0 + s * nthr;            // 262144 quads total
      float4 v0 = Xf[(size_t)qi * 2];
      float4 v1 = Xf[(size_t)qi * 2 + 1];
      ushort4 r, im;
      r.x = f2bf(v0.x); im.x = f2bf(v0.y);
      r.y = f2bf(v0.z); im.y = f2bf(v0.w);
      r.z = f2bf(v1.x); im.z = f2bf(v1.y);
      r.w = f2bf(v1.z); im.w = f2bf(v1.w);
      *(ushort4*)(Xr + (size_t)qi * 4) = r;
      *(ushort4*)(Xi + (size_t)qi * 4) = im;
    }
  }
}

// ---------------- K2: banded mesh, one wave per basis column, shuffle exchange ----------------
// Window: 128 pairs (256 entries) centered on the column's start pair; band spread is
// <=1 pair/step so 64 steps fit with ~1-pair truncation (edge magnitude ~1e-10).
__global__ __launch_bounds__(64) void mesh_kernel(
    const float4* __restrict__ cA, const float4* __restrict__ cB,
    unsigned short* __restrict__ Ur, unsigned short* __restrict__ Ui)
{
  const int bid = blockIdx.x;
  const int j = (bid & 7) * 64 + (bid >> 3);   // bijective XCD swizzle (512 = 8*64)
  const int L = threadIdx.x;
  const int p0 = j >> 1;
  int ws = p0 - 63; ws = ws < 0 ? 0 : (ws > 128 ? 128 : ws);
  const int q0 = ws + 2 * L, q1 = q0 + 1;

  float2 xa0 = make_float2((2 * q0     == j) ? 1.f : 0.f, 0.f);
  float2 xb0 = make_float2((2 * q0 + 1 == j) ? 1.f : 0.f, 0.f);
  float2 xa1 = make_float2((2 * q1     == j) ? 1.f : 0.f, 0.f);
  float2 xb1 = make_float2((2 * q1 + 1 == j) ? 1.f : 0.f, 0.f);

  const bool hasBnd = (q1 < 255);   // boundary B-MZI p=q1 exists
  const size_t stepStride = (size_t)CSTRIDE * 2;   // float4s per step

  float4 A0, A1, A2, A3, B0, B1, B2, B3;
  {
    const float4* pa = cA + (size_t)q0 * 2;
    const float4* pb = cB + (size_t)q0 * 2;
    A0 = pa[0]; A1 = pa[1]; A2 = pa[2]; A3 = pa[3];
    B0 = pb[0]; B1 = pb[1]; B2 = pb[2]; B3 = pb[3];
  }

  for (int l = 0; l < LSTEPS; ++l) {
    // prefetch next step's coeffs (stay in flight under this step's compute)
    const int lp = (l + 1 < LSTEPS) ? l + 1 : l;
    const float4* pa = cA + (size_t)lp * stepStride + (size_t)q0 * 2;
    const float4* pb = cB + (size_t)lp * stepStride + (size_t)q0 * 2;
    float4 nA0 = pa[0], nA1 = pa[1], nA2 = pa[2], nA3 = pa[3];
    float4 nB0 = pb[0], nB1 = pb[1], nB2 = pb[2], nB3 = pb[3];

    // ---- layer A (both pairs local) ----
    {
      float2 c1 = make_float2(A0.x, A0.y), c2 = make_float2(A0.z, A0.w);
      float2 c3 = make_float2(A1.x, A1.y), c4 = make_float2(A1.z, A1.w);
      float2 na = cfma(c2, xb0, cmul(c1, xa0));
      float2 nb = cfma(c4, xb0, cmul(c3, xa0));
      xa0 = na; xb0 = nb;
    }
    {
      float2 c1 = make_float2(A2.x, A2.y), c2 = make_float2(A2.z, A2.w);
      float2 c3 = make_float2(A3.x, A3.y), c4 = make_float2(A3.z, A3.w);
      float2 na = cfma(c2, xb1, cmul(c1, xa1));
      float2 nb = cfma(c4, xb1, cmul(c3, xa1));
      xa1 = na; xb1 = nb;
    }

    // neighbor's post-A xa0 (pair q1+1) from lane L+1
    float xnx = __shfl_down(xa0.x, 1);
    float xny = __shfl_down(xa0.y, 1);
    float2 xn = (L == 63) ? make_float2(0.f, 0.f) : make_float2(xnx, xny);

    // ---- boundary B-MZI p=q1: a=xb1, b=xn; na->xb1, nb-> next lane's xa0 ----
    float2 nbo;
    {
      float2 d1 = make_float2(B2.x, B2.y), d2 = make_float2(B2.z, B2.w);
      float2 d3 = make_float2(B3.x, B3.y), d4 = make_float2(B3.z, B3.w);
      float2 bna = cfma(d2, xn, cmul(d1, xb1));
      float2 bnb = cfma(d4, xn, cmul(d3, xb1));
      nbo = hasBnd ? bnb : make_float2(0.f, 0.f);
      if (hasBnd) xb1 = bna;
    }

    // ---- internal B-MZI p=q0: a=xb0, b=xa1 (always exists: q0<=254) ----
    {
      float2 d1 = make_float2(B0.x, B0.y), d2 = make_float2(B0.z, B0.w);
      float2 d3 = make_float2(B1.x, B1.y), d4 = make_float2(B1.z, B1.w);
      float2 ina = cfma(d2, xa1, cmul(d1, xb0));
      float2 inb = cfma(d4, xa1, cmul(d3, xb0));
      xb0 = ina; xa1 = inb;
    }

    // receive new xa0 from lane L-1's boundary output
    float px = __shfl_up(nbo.x, 1);
    float py = __shfl_up(nbo.y, 1);
    if (L > 0) xa0 = make_float2(px, py);
    // (L==0: global pair-0 xa passes through, or window-edge approximation)

    A0 = nA0; A1 = nA1; A2 = nA2; A3 = nA3;
    B0 = nB0; B1 = nB1; B2 = nB2; B3 = nB3;
  }

  // scatter column j into zeroed U planes (N-form: U[i][j])
  const int rows[4] = {2 * q0, 2 * q0 + 1, 2 * q1, 2 * q1 + 1};
  const float2 vals[4] = {xa0, xb0, xa1, xb1};
#pragma unroll
  for (int e = 0; e < 4; ++e) {
    Ur[(size_t)rows[e] * NF + j] = f2bf(vals[e].x);
    Ui[(size_t)rows[e] * NF + j] = f2bf(vals[e].y);
  }
}

// ---------------- K3: banded complex GEMM  Y[r][i] = (sum_j X[r][j]*U[i][j]) * e^{i w_i} ----------------
#define LDT 72   // LDS leading dim (pad 64->72: 144B row stride -> 2 lanes/bank = free)

__global__ __launch_bounds__(256) void cgemm_kernel(
    const unsigned short* __restrict__ Xr, const unsigned short* __restrict__ Xi,
    const unsigned short* __restrict__ Ur, const unsigned short* __restrict__ Ui,
    const float* __restrict__ omega,
    float2* __restrict__ Y)
{
  __shared__ __align__(16) unsigned short Ars[64][LDT];
  __shared__ __align__(16) unsigned short Ais[64][LDT];
  __shared__ __align__(16) unsigned short Brs[64][LDT];
  __shared__ __align__(16) unsigned short Bis[64][LDT];

  const int tid = threadIdx.x;
  const int w = tid >> 6;          // wave 0..3 (M-split)
  const int l = tid & 63;
  const int bm = (blockIdx.x & 31) * 64;
  const int bn = (blockIdx.x >> 5) * 64;

  // band limits: U[i][j] nonzero only for |i-j| <~ 130 (use 132 margin), tile-aligned
  int klo = bn - 132; klo = klo < 0 ? 0 : klo; klo &= ~63;
  int khi = bn + 196; khi = khi > NF ? NF : khi; khi = (khi + 63) & ~63;

  f32x4 acc_r[4], acc_i[4];
#pragma unroll
  for (int nf = 0; nf < 4; ++nf) {
    acc_r[nf] = (f32x4){0.f, 0.f, 0.f, 0.f};
    acc_i[nf] = (f32x4){0.f, 0.f, 0.f, 0.f};
  }

  const int sr = tid >> 2;          // row 0..63 within tile
  const int sk = (tid & 3) * 16;    // k offset {0,16,32,48}

  for (int k0 = klo; k0 < khi; k0 += 64) {
    const uint4* gar = (const uint4*)(Xr + (size_t)(bm + sr) * NF + k0 + sk);
    const uint4* gai = (const uint4*)(Xi + (size_t)(bm + sr) * NF + k0 + sk);
    const uint4* gbr = (const uint4*)(Ur + (size_t)(bn + sr) * NF + k0 + sk);
    const uint4* gbi = (const uint4*)(Ui + (size_t)(bn + sr) * NF + k0 + sk);
    uint4 ar0 = gar[0], ar1 = gar[1];
    uint4 ai0 = gai[0], ai1 = gai[1];
    uint4 br0 = gbr[0], br1 = gbr[1];
    uint4 bi0 = gbi[0], bi1 = gbi[1];

    if (k0 > klo) __syncthreads();   // previous compute done reading LDS

    *(uint4*)&Ars[sr][sk]     = ar0;
    *(uint4*)&Ars[sr][sk + 8] = ar1;
    *(uint4*)&Ais[sr][sk]     = ai0;
    *(uint4*)&Ais[sr][sk + 8] = ai1;
    *(uint4*)&Brs[sr][sk]     = br0;
    *(uint4*)&Brs[sr][sk + 8] = br1;
    *(uint4*)&Bis[sr][sk]     = bi0;
    *(uint4*)&Bis[sr][sk + 8] = bi1;

    __syncthreads();

#pragma unroll
    for (int kk = 0; kk < 2; ++kk) {
      const int ko = kk * 32 + (l >> 4) * 8;
      bf16x8 afr = *(const bf16x8*)&Ars[w * 16 + (l & 15)][ko];
      bf16x8 afi = *(const bf16x8*)&Ais[w * 16 + (l & 15)][ko];
      i32x4 neg = (i32x4)afi ^ (int)0x80008000;
      bf16x8 afin = (bf16x8)neg;     // -Ai
#pragma unroll
      for (int nf = 0; nf < 4; ++nf) {
        bf16x8 bfr = *(const bf16x8*)&Brs[nf * 16 + (l & 15)][ko];
        bf16x8 bfi = *(const bf16x8*)&Bis[nf * 16 + (l & 15)][ko];
        acc_r[nf] = __builtin_amdgcn_mfma_f32_16x16x32_bf16(afr,  bfr, acc_r[nf], 0, 0, 0);
        acc_r[nf] = __builtin_amdgcn_mfma_f32_16x16x32_bf16(afin, bfi, acc_r[nf], 0, 0, 0);
        acc_i[nf] = __builtin_amdgcn_mfma_f32_16x16x32_bf16(afr,  bfi, acc_i[nf], 0, 0, 0);
        acc_i[nf] = __builtin_amdgcn_mfma_f32_16x16x32_bf16(afi,  bfr, acc_i[nf], 0, 0, 0);
      }
    }
  }

  // epilogue: multiply by e^{i*omega[n]} (n = output feature), store f32 complex
  const int dn0 = bn + (l & 15);
  const int dm0 = bm + w * 16 + (l >> 4) * 4;
#pragma unroll
  for (int nf = 0; nf < 4; ++nf) {
    const int n = dn0 + nf * 16;
    float sn, cn;
    sincosf(omega[n], &sn, &cn);
#pragma unroll
    for (int r = 0; r < 4; ++r) {
      float yr = acc_r[nf][r], yi = acc_i[nf][r];
      Y[(size_t)(dm0 + r) * NF + n] =
          make_float2(fmaf(yr, cn, -(yi * sn)), fmaf(yr, sn, yi * cn));
    }
  }
}

extern "C" void kernel_launch(void* const* d_in, const int* in_sizes, int n_in,
                              void* d_out, int out_size, void* d_ws, size_t ws_size,
                              hipStream_t stream) {
  const float* cmplx = (const float*)d_in[0];   // (2048, 512, 2) f32
  const float* a0    = (const float*)d_in[1];   // (64, 256)
  const float* a1    = (const float*)d_in[2];
  const float* b0    = (const float*)d_in[3];   // (64, 255)
  const float* b1    = (const float*)d_in[4];
  const float* omega = (const float*)d_in[5];   // (512,)

  size_t off = 0;
  float4* cA = (float4*)((char*)d_ws + off); off += (size_t)LSTEPS * CSTRIDE * 2 * sizeof(float4); // 512KB
  float4* cB = (float4*)((char*)d_ws + off); off += (size_t)LSTEPS * CSTRIDE * 2 * sizeof(float4); // 512KB
  unsigned short* Ur = (unsigned short*)((char*)d_ws + off); off += (size_t)NF * NF * 2;           // 512KB
  unsigned short* Ui = (unsigned short*)((char*)d_ws + off); off += (size_t)NF * NF * 2;           // 512KB
  unsigned short* Xr = (unsigned short*)((char*)d_ws + off); off += (size_t)MB * NF * 2;           // 2MB
  unsigned short* Xi = (unsigned short*)((char*)d_ws + off); off += (size_t)MB * NF * 2;           // 2MB

  prep_kernel<<<224, 256, 0, stream>>>(a0, a1, b0, b1, (const float4*)cmplx,
                                       cA, cB, Ur, Ui, Xr, Xi);
  mesh_kernel<<<512, 64, 0, stream>>>(cA, cB, Ur, Ui);
  cgemm_kernel<<<256, 256, 0, stream>>>(Xr, Xi, Ur, Ui, omega, (float2*)d_out);
}

// Round 6
// 50.144 us; speedup vs baseline: 1.3785x; 1.0826x over previous
//
#include <hip/hip_runtime.h>

#define LSTEPS 64
#define NF 512
#define MB 2048
#define CSTRIDE 256   // padded per-step pair stride for cA/cB (in float4-pairs)

typedef __attribute__((ext_vector_type(8))) short bf16x8;
typedef __attribute__((ext_vector_type(4))) float f32x4;
typedef __attribute__((ext_vector_type(4))) int i32x4;

__device__ __forceinline__ float2 cmul(float2 a, float2 b) {
  return make_float2(fmaf(a.x, b.x, -(a.y * b.y)), fmaf(a.x, b.y, a.y * b.x));
}
__device__ __forceinline__ float2 cfma(float2 a, float2 b, float2 c) {
  return make_float2(fmaf(a.x, b.x, fmaf(-a.y, b.y, c.x)),
                     fmaf(a.x, b.y, fmaf(a.y, b.x, c.y)));
}
__device__ __forceinline__ unsigned short f2bf(float f) {
  union { float f; unsigned u; } v; v.f = f;
  unsigned r = v.u + 0x7FFF + ((v.u >> 16) & 1);
  return (unsigned short)(r >> 16);
}

// ---------------- K1: coeffs (incl. zero-fill of cB pair 255) + X->bf16 planes ----------------
__global__ __launch_bounds__(256) void prep_kernel(
    const float* __restrict__ a0, const float* __restrict__ a1,
    const float* __restrict__ b0, const float* __restrict__ b1,
    const float4* __restrict__ Xf,     // (2048*512/2) float4 = 2 complex each
    float4* __restrict__ cA, float4* __restrict__ cB,
    unsigned short* __restrict__ Xr, unsigned short* __restrict__ Xi)
{
  const int bid = blockIdx.x, tid = threadIdx.x;
  if (bid < 64) {
    const int l = bid;
    {
      float ang0 = a0[l * 256 + tid], ang1 = a1[l * 256 + tid];
      float se, ce, st, ct;
      sincosf(ang0, &se, &ce);
      sincosf(ang1, &st, &ct);
      float2 ephi = make_float2(ce, se);
      float2 tt = make_float2(0.5f * (ct - 1.0f), 0.5f * st);
      float2 uu = make_float2(0.5f * (ct + 1.0f), 0.5f * st);
      float2 C1 = cmul(ephi, tt);
      float2 C2 = make_float2(-uu.y, uu.x);
      float2 eu = cmul(ephi, uu);
      float2 C3 = make_float2(-eu.y, eu.x);
      float2 C4 = make_float2(-tt.x, -tt.y);
      float4* dst = cA + (size_t)(l * CSTRIDE + tid) * 2;
      dst[0] = make_float4(C1.x, C1.y, C2.x, C2.y);
      dst[1] = make_float4(C3.x, C3.y, C4.x, C4.y);
    }
    if (tid < 255) {
      float ang0 = b0[l * 255 + tid], ang1 = b1[l * 255 + tid];
      float se, ce, st, ct;
      sincosf(ang0, &se, &ce);
      sincosf(ang1, &st, &ct);
      float2 ephi = make_float2(ce, se);
      float2 tt = make_float2(0.5f * (ct - 1.0f), 0.5f * st);
      float2 uu = make_float2(0.5f * (ct + 1.0f), 0.5f * st);
      float2 C1 = cmul(ephi, tt);
      float2 C2 = make_float2(-uu.y, uu.x);
      float2 eu = cmul(ephi, uu);
      float2 C3 = make_float2(-eu.y, eu.x);
      float2 C4 = make_float2(-tt.x, -tt.y);
      float4* dst = cB + (size_t)(l * CSTRIDE + tid) * 2;
      dst[0] = make_float4(C1.x, C1.y, C2.x, C2.y);
      dst[1] = make_float4(C3.x, C3.y, C4.x, C4.y);
    } else {
      // zero-fill the padded B pair 255 so NO read in the chain is ever unwritten
      float4* dst = cB + (size_t)(l * CSTRIDE + 255) * 2;
      dst[0] = make_float4(0.f, 0.f, 0.f, 0.f);
      dst[1] = make_float4(0.f, 0.f, 0.f, 0.f);
    }
  } else {
    // X (float2) -> bf16 planes: 1024 blocks x 256 thr, 1 quad (4 complex) each
    const int qi = (bid - 64) * 256 + tid;       // 0..262143
    float4 v0 = Xf[(size_t)qi * 2];
    float4 v1 = Xf[(size_t)qi * 2 + 1];
    ushort4 r, im;
    r.x = f2bf(v0.x); im.x = f2bf(v0.y);
    r.y = f2bf(v0.z); im.y = f2bf(v0.w);
    r.z = f2bf(v1.x); im.z = f2bf(v1.y);
    r.w = f2bf(v1.z); im.w = f2bf(v1.w);
    *(ushort4*)(Xr + (size_t)qi * 4) = r;
    *(ushort4*)(Xi + (size_t)qi * 4) = im;
  }
}

// ---------------- K2: banded mesh, 2 columns per wave, full-column writes ----------------
struct MZS { float2 a0, b0, a1, b1; };

__device__ __forceinline__ void mzi_apply(const float4& k0, const float4& k1,
                                          float2& a, float2& b) {
  float2 c1 = make_float2(k0.x, k0.y), c2 = make_float2(k0.z, k0.w);
  float2 c3 = make_float2(k1.x, k1.y), c4 = make_float2(k1.z, k1.w);
  float2 na = cfma(c2, b, cmul(c1, a));
  float2 nb = cfma(c4, b, cmul(c3, a));
  a = na; b = nb;
}
// boundary B-MZI: a updated only if en; returns (en ? nb : 0)
__device__ __forceinline__ float2 mzi_bnd(const float4& k0, const float4& k1,
                                          float2& a, float2 b, bool en) {
  float2 d1 = make_float2(k0.x, k0.y), d2 = make_float2(k0.z, k0.w);
  float2 d3 = make_float2(k1.x, k1.y), d4 = make_float2(k1.z, k1.w);
  float2 na = cfma(d2, b, cmul(d1, a));
  float2 nb = cfma(d4, b, cmul(d3, a));
  if (en) a = na;
  return en ? nb : make_float2(0.f, 0.f);
}

__device__ __forceinline__ void load_bank(float4 (&K)[8],
    const float4* __restrict__ cA, const float4* __restrict__ cB, int l, int q0)
{
  const float4* pa = cA + (size_t)l * (CSTRIDE * 2) + (size_t)q0 * 2;
  const float4* pb = cB + (size_t)l * (CSTRIDE * 2) + (size_t)q0 * 2;
  K[0] = pa[0]; K[1] = pa[1]; K[2] = pa[2]; K[3] = pa[3];
  K[4] = pb[0]; K[5] = pb[1]; K[6] = pb[2]; K[7] = pb[3];
}

__device__ __forceinline__ void step_state(const float4 (&K)[8], int L, bool hasBnd,
                                           MZS& s)
{
  mzi_apply(K[0], K[1], s.a0, s.b0);          // layer A, pair q0
  mzi_apply(K[2], K[3], s.a1, s.b1);          // layer A, pair q1
  float xnx = __shfl_down(s.a0.x, 1);         // neighbor's post-A a0 (pair q1+1)
  float xny = __shfl_down(s.a0.y, 1);
  float2 xn = (L == 63) ? make_float2(0.f, 0.f) : make_float2(xnx, xny);
  float2 nbo = mzi_bnd(K[6], K[7], s.b1, xn, hasBnd);   // boundary B, pair q1
  mzi_apply(K[4], K[5], s.b0, s.a1);          // internal B, pair q0
  float px = __shfl_up(nbo.x, 1);
  float py = __shfl_up(nbo.y, 1);
  if (L > 0) s.a0 = make_float2(px, py);
}

__global__ __launch_bounds__(64) void mesh_kernel(
    const float4* __restrict__ cA, const float4* __restrict__ cB,
    unsigned short* __restrict__ Ur, unsigned short* __restrict__ Ui)
{
  const int bid = blockIdx.x;
  const int c = (bid & 7) * 32 + (bid >> 3);   // bijective XCD swizzle (256 = 8*32)
  const int L = threadIdx.x;
  // columns j0=2c, j1=2c+1 share impulse pair p0=c -> same window
  int ws = c - 63; ws = ws < 0 ? 0 : (ws > 128 ? 128 : ws);
  const int q0 = ws + 2 * L, q1 = q0 + 1;
  const bool hasBnd = (q1 < 255);

  MZS s0, s1;   // state for column j0 (impulse at row 2c) and j1 (row 2c+1)
  s0.a0 = make_float2((q0 == c) ? 1.f : 0.f, 0.f);
  s0.b0 = make_float2(0.f, 0.f);
  s0.a1 = make_float2((q1 == c) ? 1.f : 0.f, 0.f);
  s0.b1 = make_float2(0.f, 0.f);
  s1.a0 = make_float2(0.f, 0.f);
  s1.b0 = make_float2((q0 == c) ? 1.f : 0.f, 0.f);
  s1.a1 = make_float2(0.f, 0.f);
  s1.b1 = make_float2((q1 == c) ? 1.f : 0.f, 0.f);

  float4 K0[8], K1[8], K2[8];
  load_bank(K0, cA, cB, 0, q0);
  load_bank(K1, cA, cB, 1, q0);
  load_bank(K2, cA, cB, 2, q0);

#pragma unroll 1
  for (int l = 0; l < 63; l += 3) {
    step_state(K0, L, hasBnd, s0); step_state(K0, L, hasBnd, s1);
    load_bank(K0, cA, cB, (l + 3 < 64) ? l + 3 : 63, q0);
    step_state(K1, L, hasBnd, s0); step_state(K1, L, hasBnd, s1);
    load_bank(K1, cA, cB, (l + 4 < 64) ? l + 4 : 63, q0);
    step_state(K2, L, hasBnd, s0); step_state(K2, L, hasBnd, s1);
    load_bank(K2, cA, cB, (l + 5 < 64) ? l + 5 : 63, q0);
  }
  step_state(K0, L, hasBnd, s0); step_state(K0, L, hasBnd, s1);   // step 63

  // ---- write the FULL columns j0,j1 (packed 4B stores): in-window values + zeros ----
  unsigned* Ur32 = (unsigned*)Ur;
  unsigned* Ui32 = (unsigned*)Ui;
  const int rows[4] = {2 * q0, 2 * q0 + 1, 2 * q1, 2 * q1 + 1};
  const float2 v0[4] = {s0.a0, s0.b0, s0.a1, s0.b1};
  const float2 v1[4] = {s1.a0, s1.b0, s1.a1, s1.b1};
#pragma unroll
  for (int e = 0; e < 4; ++e) {
    unsigned pr = (unsigned)f2bf(v0[e].x) | ((unsigned)f2bf(v1[e].x) << 16);
    unsigned pi = (unsigned)f2bf(v0[e].y) | ((unsigned)f2bf(v1[e].y) << 16);
    Ur32[(size_t)rows[e] * (NF / 2) + c] = pr;
    Ui32[(size_t)rows[e] * (NF / 2) + c] = pi;
  }
#pragma unroll
  for (int e = 0; e < 4; ++e) {
    const int row = (2 * ws + 256 + 4 * L + e) & 511;   // the 256 out-of-window rows
    Ur32[(size_t)row * (NF / 2) + c] = 0u;
    Ui32[(size_t)row * (NF / 2) + c] = 0u;
  }
}

// ---------------- K3: banded complex GEMM, BM=32 -> 512 blocks ----------------
#define BMT 32
#define BNT 64
#define LDT 72   // pad 64->72 bf16

__global__ __launch_bounds__(256) void cgemm_kernel(
    const unsigned short* __restrict__ Xr, const unsigned short* __restrict__ Xi,
    const unsigned short* __restrict__ Ur, const unsigned short* __restrict__ Ui,
    const float* __restrict__ omega,
    float2* __restrict__ Y)
{
  __shared__ __align__(16) unsigned short Ars[BMT][LDT];
  __shared__ __align__(16) unsigned short Ais[BMT][LDT];
  __shared__ __align__(16) unsigned short Brs[BNT][LDT];
  __shared__ __align__(16) unsigned short Bis[BNT][LDT];

  const int tid = threadIdx.x;
  const int w = tid >> 6;
  const int wm = w & 1;            // m-half (16 rows)
  const int wn = w >> 1;           // n-half (32 cols)
  const int lane = tid & 63;
  const int bm = (blockIdx.x >> 3) * BMT;   // 64 m-tiles
  const int bn = (blockIdx.x & 7) * BNT;    // 8 n-tiles

  int klo = bn - 132; klo = klo < 0 ? 0 : klo; klo &= ~63;
  int khi = bn + 196; khi = khi > NF ? NF : khi; khi = (khi + 63) & ~63;

  f32x4 acc_r[2], acc_i[2];
#pragma unroll
  for (int nf = 0; nf < 2; ++nf) {
    acc_r[nf] = (f32x4){0.f, 0.f, 0.f, 0.f};
    acc_i[nf] = (f32x4){0.f, 0.f, 0.f, 0.f};
  }

  const int sar = tid >> 3, sak = (tid & 7) * 8;
  const int sbr = tid >> 2, sbk = (tid & 3) * 16;

  for (int k0 = klo; k0 < khi; k0 += 64) {
    const uint4* gar = (const uint4*)(Xr + (size_t)(bm + sar) * NF + k0 + sak);
    const uint4* gai = (const uint4*)(Xi + (size_t)(bm + sar) * NF + k0 + sak);
    const uint4* gbr = (const uint4*)(Ur + (size_t)(bn + sbr) * NF + k0 + sbk);
    const uint4* gbi = (const uint4*)(Ui + (size_t)(bn + sbr) * NF + k0 + sbk);
    uint4 ar = gar[0];
    uint4 ai = gai[0];
    uint4 br0 = gbr[0], br1 = gbr[1];
    uint4 bi0 = gbi[0], bi1 = gbi[1];

    if (k0 > klo) __syncthreads();

    *(uint4*)&Ars[sar][sak]     = ar;
    *(uint4*)&Ais[sar][sak]     = ai;
    *(uint4*)&Brs[sbr][sbk]     = br0;
    *(uint4*)&Brs[sbr][sbk + 8] = br1;
    *(uint4*)&Bis[sbr][sbk]     = bi0;
    *(uint4*)&Bis[sbr][sbk + 8] = bi1;

    __syncthreads();

#pragma unroll
    for (int kk = 0; kk < 2; ++kk) {
      const int ko = kk * 32 + (lane >> 4) * 8;
      bf16x8 afr = *(const bf16x8*)&Ars[wm * 16 + (lane & 15)][ko];
      bf16x8 afi = *(const bf16x8*)&Ais[wm * 16 + (lane & 15)][ko];
      i32x4 neg = (i32x4)afi ^ (int)0x80008000;
      bf16x8 afin = (bf16x8)neg;     // -Ai
#pragma unroll
      for (int nf = 0; nf < 2; ++nf) {
        bf16x8 bfr = *(const bf16x8*)&Brs[wn * 32 + nf * 16 + (lane & 15)][ko];
        bf16x8 bfi = *(const bf16x8*)&Bis[wn * 32 + nf * 16 + (lane & 15)][ko];
        acc_r[nf] = __builtin_amdgcn_mfma_f32_16x16x32_bf16(afr,  bfr, acc_r[nf], 0, 0, 0);
        acc_r[nf] = __builtin_amdgcn_mfma_f32_16x16x32_bf16(afin, bfi, acc_r[nf], 0, 0, 0);
        acc_i[nf] = __builtin_amdgcn_mfma_f32_16x16x32_bf16(afr,  bfi, acc_i[nf], 0, 0, 0);
        acc_i[nf] = __builtin_amdgcn_mfma_f32_16x16x32_bf16(afi,  bfr, acc_i[nf], 0, 0, 0);
      }
    }
  }

  const int dn0 = bn + wn * 32 + (lane & 15);
  const int dm0 = bm + wm * 16 + (lane >> 4) * 4;
#pragma unroll
  for (int nf = 0; nf < 2; ++nf) {
    const int n = dn0 + nf * 16;
    float sn, cn;
    sincosf(omega[n], &sn, &cn);
#pragma unroll
    for (int r = 0; r < 4; ++r) {
      float yr = acc_r[nf][r], yi = acc_i[nf][r];
      Y[(size_t)(dm0 + r) * NF + n] =
          make_float2(fmaf(yr, cn, -(yi * sn)), fmaf(yr, sn, yi * cn));
    }
  }
}

extern "C" void kernel_launch(void* const* d_in, const int* in_sizes, int n_in,
                              void* d_out, int out_size, void* d_ws, size_t ws_size,
                              hipStream_t stream) {
  const float* cmplx = (const float*)d_in[0];   // (2048, 512, 2) f32
  const float* a0    = (const float*)d_in[1];
  const float* a1    = (const float*)d_in[2];
  const float* b0    = (const float*)d_in[3];
  const float* b1    = (const float*)d_in[4];
  const float* omega = (const float*)d_in[5];

  size_t off = 0;
  float4* cA = (float4*)((char*)d_ws + off); off += (size_t)LSTEPS * CSTRIDE * 2 * sizeof(float4);
  float4* cB = (float4*)((char*)d_ws + off); off += (size_t)LSTEPS * CSTRIDE * 2 * sizeof(float4);
  unsigned short* Ur = (unsigned short*)((char*)d_ws + off); off += (size_t)NF * NF * 2;
  unsigned short* Ui = (unsigned short*)((char*)d_ws + off); off += (size_t)NF * NF * 2;
  unsigned short* Xr = (unsigned short*)((char*)d_ws + off); off += (size_t)MB * NF * 2;
  unsigned short* Xi = (unsigned short*)((char*)d_ws + off); off += (size_t)MB * NF * 2;

  prep_kernel<<<1088, 256, 0, stream>>>(a0, a1, b0, b1, (const float4*)cmplx,
                                        cA, cB, Xr, Xi);
  mesh_kernel<<<256, 64, 0, stream>>>(cA, cB, Ur, Ui);
  cgemm_kernel<<<(MB / BMT) * (NF / BNT), 256, 0, stream>>>(
      Xr, Xi, Ur, Ui, omega, (float2*)d_out);
}